// Round 3
// baseline (303.303 us; speedup 1.0000x reference)
//
#include <hip/hip_runtime.h>
#include <hip/hip_bf16.h>
#include <stdint.h>

// deform_conv2d: N=8, C=256, H=W=64, OC=256, 3x3, stride=1, pad=1 -> OH=OW=64
// im2col-fused MFMA GEMM. M=32768 (n,oh,ow), N=256 oc, K=2304 (kd = k*256+c).
// R3: latency-bound fix -- M-split to 1024 blocks (32-row tiles) for ~5 blocks/CU
//     occupancy; af ds_reads hoisted BEFORE stage ds_writes so fine-grained
//     lgkmcnt lets MFMA(t) proceed without draining STAGE(t+1).

typedef short short8 __attribute__((ext_vector_type(8)));
typedef float f32x4 __attribute__((ext_vector_type(4)));

__device__ __forceinline__ float bflo(uint32_t u) { return __uint_as_float(u << 16); }
__device__ __forceinline__ float bfhi(uint32_t u) { return __uint_as_float(u & 0xffff0000u); }
__device__ __forceinline__ uint32_t packbf(float a, float b) {
  unsigned short ua = __builtin_bit_cast(unsigned short, __float2bfloat16(a));
  unsigned short ub = __builtin_bit_cast(unsigned short, __float2bfloat16(b));
  return (uint32_t)ua | ((uint32_t)ub << 16);
}

// ---- prep 1: x NCHW fp32 -> NHWC bf16 (LDS transpose, 64x64 tiles) ----
__global__ __launch_bounds__(256) void prep_x_kernel(const float* __restrict__ x,
                                                     unsigned short* __restrict__ xb) {
  __shared__ float tile[64][65];
  int bn   = blockIdx.x >> 8;
  int rem  = blockIdx.x & 255;
  int y    = rem >> 2;
  int cblk = rem & 3;
  int tid  = threadIdx.x;
  {
    int xcol = tid & 63;
    int cl0  = tid >> 6;
#pragma unroll
    for (int i = 0; i < 16; ++i) {
      int cl = cl0 + i * 4;
      tile[cl][xcol] = x[((bn * 256 + cblk * 64 + cl) * 64 + y) * 64 + xcol];
    }
  }
  __syncthreads();
  {
    int cl  = tid & 63;
    int xc0 = tid >> 6;
#pragma unroll
    for (int i = 0; i < 16; ++i) {
      int xc = xc0 + i * 4;
      xb[((bn * 64 + y) * 64 + xc) * 256 + cblk * 64 + cl] =
          __builtin_bit_cast(unsigned short, __float2bfloat16(tile[cl][xc]));
    }
  }
}

// ---- prep 2: weight -> bf16, layout w3[(t*256 + oc)*64 + kk], kd = k*256+c ----
__global__ __launch_bounds__(256) void prep_w_kernel(const float* __restrict__ w,
                                                     unsigned short* __restrict__ w3) {
  int idx = blockIdx.x * 256 + threadIdx.x;
  int t   = idx >> 14;
  int r2  = idx & 16383;
  int oc  = r2 >> 6;
  int kk  = r2 & 63;
  int c   = (t & 3) * 64 + kk;
  int k   = t >> 2;
  w3[idx] = __builtin_bit_cast(unsigned short, __float2bfloat16(w[(oc * 256 + c) * 9 + k]));
}

// ---- main fused kernel: 1024 blocks = (bn, oh, ow-half); tile 32 rows x 256 oc ----
__global__ __launch_bounds__(256, 5) void deform_mfma_kernel(
    const unsigned short* __restrict__ xb,    // NHWC bf16
    const float* __restrict__ offset,         // (8, 18, 64, 64) fp32
    const unsigned short* __restrict__ w3,    // chunk-major bf16
    float* __restrict__ out) {                // (8, 256, 64, 64) fp32
  __shared__ __align__(16) unsigned short At0[32 * 72];
  __shared__ __align__(16) unsigned short At1[32 * 72];
  __shared__ float4 cw[288];   // bilinear corner weights (validity folded in)
  __shared__ int4   cp[288];   // clamped corner BYTE offsets into NHWC plane

  // XCD swizzle: blockIdx%8 ~ XCD id -> per-XCD working set (xb slice + w3) fits L2
  int bn     = blockIdx.x & 7;
  int rem    = blockIdx.x >> 3;    // 0..127
  int oh     = rem >> 1;
  int owbase = (rem & 1) * 32;
  int tid    = threadIdx.x;

  // ---- per-block coordinate precompute: 32 ow x 9 taps ----
  for (int e = tid; e < 288; e += 256) {
    int r  = e & 31;          // ow within half-row
    int k  = e >> 5;          // tap 0..8
    int ky = k / 3 - 1;
    int kx = k % 3 - 1;
    float offy = offset[((bn * 18 + 2 * k    ) * 64 + oh) * 64 + owbase + r];
    float offx = offset[((bn * 18 + 2 * k + 1) * 64 + oh) * 64 + owbase + r];
    float y = (float)(oh + ky) + offy;
    float x = (float)(owbase + r + kx) + offx;
    float y0f = floorf(y), x0f = floorf(x);
    float fy = y - y0f, fx = x - x0f;
    int y0 = (int)y0f, x0 = (int)x0f;
    int y1 = y0 + 1, x1 = x0 + 1;
    float vy0 = (y0 >= 0 && y0 <= 63) ? 1.0f : 0.0f;
    float vy1 = (y1 >= 0 && y1 <= 63) ? 1.0f : 0.0f;
    float vx0 = (x0 >= 0 && x0 <= 63) ? 1.0f : 0.0f;
    float vx1 = (x1 >= 0 && x1 <= 63) ? 1.0f : 0.0f;
    float wy0 = (1.0f - fy) * vy0, wy1 = fy * vy1;
    float wx0 = (1.0f - fx) * vx0, wx1 = fx * vx1;
    cw[e] = make_float4(wy0 * wx0, wy0 * wx1, wy1 * wx0, wy1 * wx1);
    int y0c = min(max(y0, 0), 63), y1c = min(max(y1, 0), 63);
    int x0c = min(max(x0, 0), 63), x1c = min(max(x1, 0), 63);
    cp[e] = make_int4((y0c * 64 + x0c) * 512, (y0c * 64 + x1c) * 512,
                      (y1c * 64 + x0c) * 512, (y1c * 64 + x1c) * 512);
  }

  int wave  = tid >> 6;
  int lane  = tid & 63;
  int half  = lane >> 5;           // half-wave handles one row
  int cpair = (lane & 31) * 2;     // 2 channels per lane
  int mrow  = lane & 15;
  int quad  = lane >> 4;
  int wv8   = wave * 8;

  f32x4 acc[2][4] = {};
  const unsigned short* xbn = xb + (size_t)bn * (64 * 64 * 256);

  // stage chunk TT into LDS buffer DST (bilinear sample 32 rows x 64 ch)
#define STAGE(TT, DST)                                                          \
  {                                                                             \
    int k_  = (TT) >> 2;                                                        \
    const char* gb_ = (const char*)(xbn + ((TT) & 3) * 64 + cpair);             \
    _Pragma("unroll")                                                           \
    for (int j = 0; j < 4; ++j) {                                               \
      int r_ = wv8 + j * 2 + half;                                              \
      int e_ = k_ * 32 + r_;                                                    \
      float4 w_ = cw[e_];                                                       \
      int4   p_ = cp[e_];                                                       \
      uint32_t u00 = *(const uint32_t*)(gb_ + p_.x);                            \
      uint32_t u01 = *(const uint32_t*)(gb_ + p_.y);                            \
      uint32_t u10 = *(const uint32_t*)(gb_ + p_.z);                            \
      uint32_t u11 = *(const uint32_t*)(gb_ + p_.w);                            \
      float a0 = bflo(u00) * w_.x + bflo(u01) * w_.y + bflo(u10) * w_.z + bflo(u11) * w_.w; \
      float a1 = bfhi(u00) * w_.x + bfhi(u01) * w_.y + bfhi(u10) * w_.z + bfhi(u11) * w_.w; \
      *(uint32_t*)(&(DST)[r_ * 72 + cpair]) = packbf(a0, a1);                   \
    }                                                                           \
  }

  // read A fragments for the CURRENT chunk from SRC -- issued FIRST in the
  // chunk body so lgkmcnt for these ds_reads doesn't drain the stage ds_writes
#define AFREAD(SRC)                                                             \
  {                                                                             \
    _Pragma("unroll")                                                           \
    for (int m = 0; m < 2; ++m)                                                 \
      _Pragma("unroll")                                                         \
      for (int ks = 0; ks < 2; ++ks)                                            \
        af[m][ks] = *(const short8*)(&(SRC)[(m * 16 + mrow) * 72 + ks * 32 + quad * 8]); \
  }

  // load the 8 B-fragments for chunk TT straight from global (L2-resident)
#define BLOAD(TT)                                                               \
  {                                                                             \
    const short8* wb_ = (const short8*)(w3 + (TT) * 16384 + (wave * 64 + mrow) * 64 + quad * 8); \
    _Pragma("unroll")                                                           \
    for (int nn = 0; nn < 4; ++nn) {                                            \
      bfr[0][nn] = wb_[nn * 128];                                               \
      bfr[1][nn] = wb_[nn * 128 + 4];                                           \
    }                                                                           \
  }

#define MFMA_CHUNK                                                              \
  {                                                                             \
    _Pragma("unroll")                                                           \
    for (int ks = 0; ks < 2; ++ks)                                              \
      _Pragma("unroll")                                                         \
      for (int m = 0; m < 2; ++m)                                               \
        _Pragma("unroll")                                                       \
        for (int nn = 0; nn < 4; ++nn)                                          \
          acc[m][nn] = __builtin_amdgcn_mfma_f32_16x16x32_bf16(af[m][ks], bfr[ks][nn], acc[m][nn], 0, 0, 0); \
  }

  short8 af[2][2];
  short8 bfr[2][4];

  __syncthreads();           // cw/cp ready
  STAGE(0, At0)
  __syncthreads();           // At0 ready

  for (int t = 0; t < 36; t += 2) {
    // even chunk: af-reads first, then stage t+1, then MFMA
    AFREAD(At0)
    BLOAD(t)
    STAGE(t + 1, At1)
    MFMA_CHUNK
    __syncthreads();
    // odd chunk
    AFREAD(At1)
    BLOAD(t + 1)
    if (t + 2 < 36) STAGE(t + 2, At0)
    MFMA_CHUNK
    __syncthreads();
  }

  // ---- epilogue: C/D layout col=lane&15(oc), row=quad*4+reg(ow) -> float4 stores ----
  float* outp = out + (size_t)(bn * 256) * 4096 + oh * 64 + owbase;
#pragma unroll
  for (int m = 0; m < 2; ++m) {
    int ow0 = m * 16 + quad * 4;
#pragma unroll
    for (int nn = 0; nn < 4; ++nn) {
      int oc = wave * 64 + nn * 16 + mrow;
      *(f32x4*)(outp + oc * 4096 + ow0) = acc[m][nn];
    }
  }
#undef STAGE
#undef AFREAD
#undef BLOAD
#undef MFMA_CHUNK
}

extern "C" void kernel_launch(void* const* d_in, const int* in_sizes, int n_in,
                              void* d_out, int out_size, void* d_ws, size_t ws_size,
                              hipStream_t stream) {
  (void)in_sizes; (void)n_in; (void)out_size; (void)ws_size;
  const float* x      = (const float*)d_in[0];
  const float* offset = (const float*)d_in[1];
  const float* weight = (const float*)d_in[2];
  float* out = (float*)d_out;

  unsigned short* xb = (unsigned short*)d_ws;                                   // 16.78 MB
  unsigned short* w3 = (unsigned short*)((char*)d_ws + (size_t)8*64*64*256*2);  // +1.18 MB

  prep_x_kernel<<<2048, 256, 0, stream>>>(x, xb);
  prep_w_kernel<<<2304, 256, 0, stream>>>(weight, w3);
  deform_mfma_kernel<<<1024, 256, 0, stream>>>(xb, offset, w3, out);
}

// Round 4
// 176.553 us; speedup vs baseline: 1.7179x; 1.7179x over previous
//
#include <hip/hip_runtime.h>
#include <hip/hip_bf16.h>
#include <stdint.h>

// deform_conv2d: N=8, C=256, H=W=64, OC=256, 3x3, stride=1, pad=1 -> OH=OW=64
// im2col-fused MFMA GEMM. M=32768 (n,oh,ow), N=256 oc, K=2304 (kd = k*256+c).
// R4 = R1 structure (512 blocks, 64x256 tile, B in LDS) +
//   (a) XCD swizzle bn=blk&7 (R2-proven FETCH 194->14 MB),
//   (b) B staged by global_load_lds width=16 from a pre-XOR-swizzled w3 image
//       (lane-contiguous DMA, conflict-free ds_read_b128 b-frags),
//   (c) per-tap coord double-buffer (4 KB vs 18.4 KB) -> 45 KB LDS -> 3 blocks/CU.

typedef short short8 __attribute__((ext_vector_type(8)));
typedef float f32x4 __attribute__((ext_vector_type(4)));

__device__ __forceinline__ float bflo(uint32_t u) { return __uint_as_float(u << 16); }
__device__ __forceinline__ float bfhi(uint32_t u) { return __uint_as_float(u & 0xffff0000u); }
__device__ __forceinline__ uint32_t packbf(float a, float b) {
  unsigned short ua = __builtin_bit_cast(unsigned short, __float2bfloat16(a));
  unsigned short ub = __builtin_bit_cast(unsigned short, __float2bfloat16(b));
  return (uint32_t)ua | ((uint32_t)ub << 16);
}

// ---- prep 1: x NCHW fp32 -> NHWC bf16 (LDS transpose, 64x64 tiles) ----
__global__ __launch_bounds__(256) void prep_x_kernel(const float* __restrict__ x,
                                                     unsigned short* __restrict__ xb) {
  __shared__ float tile[64][65];
  int bn   = blockIdx.x >> 8;
  int rem  = blockIdx.x & 255;
  int y    = rem >> 2;
  int cblk = rem & 3;
  int tid  = threadIdx.x;
  {
    int xcol = tid & 63;
    int cl0  = tid >> 6;
#pragma unroll
    for (int i = 0; i < 16; ++i) {
      int cl = cl0 + i * 4;
      tile[cl][xcol] = x[((bn * 256 + cblk * 64 + cl) * 64 + y) * 64 + xcol];
    }
  }
  __syncthreads();
  {
    int cl  = tid & 63;
    int xc0 = tid >> 6;
#pragma unroll
    for (int i = 0; i < 16; ++i) {
      int xc = xc0 + i * 4;
      xb[((bn * 64 + y) * 64 + xc) * 256 + cblk * 64 + cl] =
          __builtin_bit_cast(unsigned short, __float2bfloat16(tile[cl][xc]));
    }
  }
}

// ---- prep 2: weight -> bf16, XOR-swizzled chunk-major image for DMA ----
// 16B unit g in [0,2048) per chunk t: oc=g>>3, logical kk8=(g&7)^(oc&7),
// unit holds B[oc][kk8*8 .. +7], kd-channel c=(t&3)*64+kk, tap k=t>>2.
__global__ __launch_bounds__(256) void prep_w_kernel(const float* __restrict__ w,
                                                     unsigned short* __restrict__ w3s) {
  int idx = blockIdx.x * 256 + threadIdx.x;   // < 589824
  int t   = idx >> 14;
  int r2  = idx & 16383;
  int g   = r2 >> 3;
  int e   = r2 & 7;
  int oc  = g >> 3;
  int kk8 = (g & 7) ^ (oc & 7);
  int kk  = kk8 * 8 + e;
  int c   = (t & 3) * 64 + kk;
  int k   = t >> 2;
  w3s[idx] = __builtin_bit_cast(unsigned short, __float2bfloat16(w[(oc * 256 + c) * 9 + k]));
}

// per-(tap,ow) bilinear coords
__device__ __forceinline__ void compute_coords(int bn, int oh, int k, int r,
                                               const float* __restrict__ offset,
                                               float4* cwp, int4* cpp) {
  int ky = k / 3 - 1;
  int kx = k % 3 - 1;
  float offy = offset[((bn * 18 + 2 * k    ) * 64 + oh) * 64 + r];
  float offx = offset[((bn * 18 + 2 * k + 1) * 64 + oh) * 64 + r];
  float y = (float)(oh + ky) + offy;
  float x = (float)(r + kx) + offx;
  float y0f = floorf(y), x0f = floorf(x);
  float fy = y - y0f, fx = x - x0f;
  int y0 = (int)y0f, x0 = (int)x0f;
  int y1 = y0 + 1, x1 = x0 + 1;
  float vy0 = (y0 >= 0 && y0 <= 63) ? 1.0f : 0.0f;
  float vy1 = (y1 >= 0 && y1 <= 63) ? 1.0f : 0.0f;
  float vx0 = (x0 >= 0 && x0 <= 63) ? 1.0f : 0.0f;
  float vx1 = (x1 >= 0 && x1 <= 63) ? 1.0f : 0.0f;
  float wy0 = (1.0f - fy) * vy0, wy1 = fy * vy1;
  float wx0 = (1.0f - fx) * vx0, wx1 = fx * vx1;
  *cwp = make_float4(wy0 * wx0, wy0 * wx1, wy1 * wx0, wy1 * wx1);
  int y0c = min(max(y0, 0), 63), y1c = min(max(y1, 0), 63);
  int x0c = min(max(x0, 0), 63), x1c = min(max(x1, 0), 63);
  *cpp = make_int4((y0c * 64 + x0c) * 512, (y0c * 64 + x1c) * 512,
                   (y1c * 64 + x0c) * 512, (y1c * 64 + x1c) * 512);
}

// ---- main fused kernel: 512 blocks = (bn, oh); tile 64 rows x 256 oc ----
__global__ __launch_bounds__(256, 3) void deform_mfma_kernel(
    const unsigned short* __restrict__ xb,    // NHWC bf16
    const float* __restrict__ offset,         // (8, 18, 64, 64) fp32
    const unsigned short* __restrict__ w3s,   // swizzled chunk-major bf16
    float* __restrict__ out) {                // (8, 256, 64, 64) fp32
  __shared__ __align__(16) unsigned short At[64 * 72];   // 9216 B, pad 72
  __shared__ __align__(16) unsigned short Bt[256 * 64];  // 32768 B, swizzled image
  __shared__ float4 cw[2][64];                           // per-tap double buffer
  __shared__ int4   cp[2][64];

  int bn  = blockIdx.x & 7;      // XCD swizzle: per-XCD working set fits L2
  int oh  = blockIdx.x >> 3;
  int tid = threadIdx.x;

  int wave  = tid >> 6;
  int lane  = tid & 63;
  int half  = lane >> 5;           // half-wave handles one row
  int cpair = (lane & 31) * 2;     // 2 channels per lane
  int mrow  = lane & 15;
  int quad  = lane >> 4;
  int wv16  = wave * 16;

  // tap 0 coords into buffer 0
  if (tid < 64) compute_coords(bn, oh, 0, tid, offset, &cw[0][tid], &cp[0][tid]);
  __syncthreads();

  f32x4 acc[4][4] = {};
  const unsigned short* xbn = xb + (size_t)bn * (64 * 64 * 256);

  for (int t = 0; t < 36; ++t) {
    int k     = t >> 2;
    int cbsel = k & 1;

    // ---- stage phase (LDS safe to overwrite: barrier at end of prev iter) ----
    // B: async DMA of the 32 KB swizzled chunk image, lane-contiguous
    {
      const unsigned short* src = w3s + t * 16384;
#pragma unroll
      for (int j = 0; j < 8; ++j) {
        int base16 = j * 256 + wave * 64;            // wave-uniform 16B-unit base
        const unsigned short* g = src + (base16 + lane) * 8;
        __builtin_amdgcn_global_load_lds(
            (const __attribute__((address_space(1))) void*)g,
            (__attribute__((address_space(3))) void*)(Bt + base16 * 8),
            16, 0, 0);
      }
    }
    // A: bilinear-sample 64 rows x 64 channels into At
    {
      const float4* cwb = cw[cbsel];
      const int4*   cpb = cp[cbsel];
      const char* gb = (const char*)(xbn + (t & 3) * 64 + cpair);
#pragma unroll
      for (int j = 0; j < 8; ++j) {
        int r = wv16 + j * 2 + half;
        float4 wv = cwb[r];
        int4   pv = cpb[r];
        uint32_t u00 = *(const uint32_t*)(gb + pv.x);
        uint32_t u01 = *(const uint32_t*)(gb + pv.y);
        uint32_t u10 = *(const uint32_t*)(gb + pv.z);
        uint32_t u11 = *(const uint32_t*)(gb + pv.w);
        float a0 = bflo(u00) * wv.x + bflo(u01) * wv.y + bflo(u10) * wv.z + bflo(u11) * wv.w;
        float a1 = bfhi(u00) * wv.x + bfhi(u01) * wv.y + bfhi(u10) * wv.z + bfhi(u11) * wv.w;
        *(uint32_t*)(&At[r * 72 + cpair]) = packbf(a0, a1);
      }
    }
    // refresh next tap's coords (used 4 chunks later; barriers guarantee visibility)
    if ((t & 3) == 0 && t < 32 && tid < 64)
      compute_coords(bn, oh, k + 1, tid, offset, &cw[cbsel ^ 1][tid], &cp[cbsel ^ 1][tid]);

    __syncthreads();   // drains DMA vmcnt + ds_writes

    // ---- compute phase ----
#pragma unroll
    for (int ks = 0; ks < 2; ++ks) {
      short8 af[4], bfr[4];
#pragma unroll
      for (int m = 0; m < 4; ++m)
        af[m] = *(const short8*)(&At[(m * 16 + mrow) * 72 + ks * 32 + quad * 8]);
#pragma unroll
      for (int nn = 0; nn < 4; ++nn) {
        int oc  = wave * 64 + nn * 16 + mrow;
        int g16 = oc * 8 + ((ks * 4 + quad) ^ (mrow & 7));   // XOR swizzle
        bfr[nn] = *(const short8*)(Bt + g16 * 8);
      }
#pragma unroll
      for (int m = 0; m < 4; ++m)
#pragma unroll
        for (int nn = 0; nn < 4; ++nn)
          acc[m][nn] = __builtin_amdgcn_mfma_f32_16x16x32_bf16(af[m], bfr[nn], acc[m][nn], 0, 0, 0);
    }
    __syncthreads();   // MFMA reads done before next stage overwrites
  }

  // ---- epilogue: C/D layout col=lane&15(oc), row=quad*4+reg(ow) -> float4 stores ----
  float* outp = out + (size_t)(bn * 256) * 4096 + oh * 64;
#pragma unroll
  for (int m = 0; m < 4; ++m) {
    int ow0 = m * 16 + quad * 4;
#pragma unroll
    for (int nn = 0; nn < 4; ++nn) {
      int oc = wave * 64 + nn * 16 + mrow;
      *(f32x4*)(outp + oc * 4096 + ow0) = acc[m][nn];
    }
  }
}

extern "C" void kernel_launch(void* const* d_in, const int* in_sizes, int n_in,
                              void* d_out, int out_size, void* d_ws, size_t ws_size,
                              hipStream_t stream) {
  (void)in_sizes; (void)n_in; (void)out_size; (void)ws_size;
  const float* x      = (const float*)d_in[0];
  const float* offset = (const float*)d_in[1];
  const float* weight = (const float*)d_in[2];
  float* out = (float*)d_out;

  unsigned short* xb  = (unsigned short*)d_ws;                                   // 16.78 MB
  unsigned short* w3s = (unsigned short*)((char*)d_ws + (size_t)8*64*64*256*2);  // +1.18 MB

  prep_x_kernel<<<2048, 256, 0, stream>>>(x, xb);
  prep_w_kernel<<<2304, 256, 0, stream>>>(weight, w3s);
  deform_mfma_kernel<<<512, 256, 0, stream>>>(xb, offset, w3s, out);
}

// Round 5
// 161.024 us; speedup vs baseline: 1.8836x; 1.0964x over previous
//
#include <hip/hip_runtime.h>
#include <hip/hip_bf16.h>
#include <stdint.h>

// deform_conv2d: N=8, C=256, H=W=64, OC=256, 3x3, stride=1, pad=1 -> OH=OW=64
// im2col-fused MFMA GEMM. M=32768 (n,oh,ow), N=256 oc, K=2304 (kd = k*256+c).
// R5: occupancy fix -- 512-thread blocks (8 waves, wave tile 32x64), grid 512
//     => 16 waves/CU (was 8). Chunk body: preload bfr regs -> barrier ->
//     issue DMA+gathers(t+1) -> MFMA(t) under in-flight loads. At double-buffered
//     (af read lazily), Bt single (bfr preloaded). XCD swizzle kept.

typedef short short8 __attribute__((ext_vector_type(8)));
typedef float f32x4 __attribute__((ext_vector_type(4)));

__device__ __forceinline__ float bflo(uint32_t u) { return __uint_as_float(u << 16); }
__device__ __forceinline__ float bfhi(uint32_t u) { return __uint_as_float(u & 0xffff0000u); }
__device__ __forceinline__ uint32_t packbf(float a, float b) {
  unsigned short ua = __builtin_bit_cast(unsigned short, __float2bfloat16(a));
  unsigned short ub = __builtin_bit_cast(unsigned short, __float2bfloat16(b));
  return (uint32_t)ua | ((uint32_t)ub << 16);
}

// ---- prep 1: x NCHW fp32 -> NHWC bf16 (LDS transpose, vectorized) ----
__global__ __launch_bounds__(256) void prep_x_kernel(const float* __restrict__ x,
                                                     unsigned short* __restrict__ xb) {
  __shared__ float tile[64][65];
  int bn   = blockIdx.x >> 8;
  int rem  = blockIdx.x & 255;
  int y    = rem >> 2;
  int cblk = rem & 3;
  int tid  = threadIdx.x;
  const float* src = x + ((size_t)(bn * 256 + cblk * 64)) * 4096 + y * 64;
#pragma unroll
  for (int i = 0; i < 4; ++i) {
    int u  = i * 256 + tid;
    int cl = u >> 4;
    int xs = (u & 15) * 4;
    float4 v = *(const float4*)(src + cl * 4096 + xs);
    tile[cl][xs] = v.x; tile[cl][xs + 1] = v.y;
    tile[cl][xs + 2] = v.z; tile[cl][xs + 3] = v.w;
  }
  __syncthreads();
  unsigned short* dst = xb + ((size_t)(bn * 64 + y) * 64) * 256 + cblk * 64;
#pragma unroll
  for (int i = 0; i < 8; ++i) {
    int v2  = i * 256 + tid;
    int xc  = v2 >> 5;
    int cl2 = (v2 & 31) * 2;
    *(uint32_t*)(dst + xc * 256 + cl2) = packbf(tile[cl2][xc], tile[cl2 + 1][xc]);
  }
}

// ---- prep 2: weight -> bf16, XOR-swizzled chunk-major image for DMA ----
__global__ __launch_bounds__(256) void prep_w_kernel(const float* __restrict__ w,
                                                     unsigned short* __restrict__ w3s) {
  int idx = blockIdx.x * 256 + threadIdx.x;   // < 589824
  int t   = idx >> 14;
  int r2  = idx & 16383;
  int g   = r2 >> 3;
  int e   = r2 & 7;
  int oc  = g >> 3;
  int kk8 = (g & 7) ^ (oc & 7);
  int kk  = kk8 * 8 + e;
  int c   = (t & 3) * 64 + kk;
  int k   = t >> 2;
  w3s[idx] = __builtin_bit_cast(unsigned short, __float2bfloat16(w[(oc * 256 + c) * 9 + k]));
}

// per-(tap,ow) bilinear coords
__device__ __forceinline__ void compute_coords(int bn, int oh, int k, int r,
                                               const float* __restrict__ offset,
                                               float4* cwp, int4* cpp) {
  int ky = k / 3 - 1;
  int kx = k % 3 - 1;
  float offy = offset[((bn * 18 + 2 * k    ) * 64 + oh) * 64 + r];
  float offx = offset[((bn * 18 + 2 * k + 1) * 64 + oh) * 64 + r];
  float y = (float)(oh + ky) + offy;
  float x = (float)(r + kx) + offx;
  float y0f = floorf(y), x0f = floorf(x);
  float fy = y - y0f, fx = x - x0f;
  int y0 = (int)y0f, x0 = (int)x0f;
  int y1 = y0 + 1, x1 = x0 + 1;
  float vy0 = (y0 >= 0 && y0 <= 63) ? 1.0f : 0.0f;
  float vy1 = (y1 >= 0 && y1 <= 63) ? 1.0f : 0.0f;
  float vx0 = (x0 >= 0 && x0 <= 63) ? 1.0f : 0.0f;
  float vx1 = (x1 >= 0 && x1 <= 63) ? 1.0f : 0.0f;
  float wy0 = (1.0f - fy) * vy0, wy1 = fy * vy1;
  float wx0 = (1.0f - fx) * vx0, wx1 = fx * vx1;
  *cwp = make_float4(wy0 * wx0, wy0 * wx1, wy1 * wx0, wy1 * wx1);
  int y0c = min(max(y0, 0), 63), y1c = min(max(y1, 0), 63);
  int x0c = min(max(x0, 0), 63), x1c = min(max(x1, 0), 63);
  *cpp = make_int4((y0c * 64 + x0c) * 512, (y0c * 64 + x1c) * 512,
                   (y1c * 64 + x0c) * 512, (y1c * 64 + x1c) * 512);
}

// ---- main: 512 blocks x 512 threads; block tile 64 rows x 256 oc; wave 32x64 ----
__global__ __launch_bounds__(512, 4) void deform_mfma_kernel(
    const unsigned short* __restrict__ xb,    // NHWC bf16
    const float* __restrict__ offset,         // (8, 18, 64, 64) fp32
    const unsigned short* __restrict__ w3s,   // swizzled chunk-major bf16
    float* __restrict__ out) {                // (8, 256, 64, 64) fp32
  __shared__ __align__(16) unsigned short At[2][64 * 72];  // 2 x 9216 B
  __shared__ __align__(16) unsigned short Bt[256 * 64];    // 32768 B, swizzled
  __shared__ float4 cw[2][64];                             // per-tap double buffer
  __shared__ int4   cp[2][64];

  int bn  = blockIdx.x & 7;      // XCD swizzle
  int oh  = blockIdx.x >> 3;
  int tid = threadIdx.x;

  int w     = tid >> 6;            // wave 0..7
  int lane  = tid & 63;
  int wrow  = w & 1;               // row half (32 rows)
  int wcol  = w >> 1;              // oc quarter (64 oc)
  int half  = lane >> 5;
  int cpair = (lane & 31) * 2;
  int mrow  = lane & 15;
  int quad  = lane >> 4;

  // taps 0 and 1 coords in parallel
  if (tid < 128) {
    int k0 = tid >> 6, r = tid & 63;
    compute_coords(bn, oh, k0, r, offset, &cw[k0][r], &cp[k0][r]);
  }
  __syncthreads();

  f32x4 acc[2][4] = {};
  const unsigned short* xbn = xb + (size_t)bn * (64 * 64 * 256);

  // stage chunk TT: B via DMA, A via bilinear gathers (8 rows per wave)
#define BDMA(TT)                                                                \
  {                                                                             \
    const unsigned short* src = w3s + (TT) * 16384;                             \
    _Pragma("unroll")                                                           \
    for (int j = 0; j < 4; ++j) {                                               \
      int base16 = j * 512 + w * 64;                                            \
      __builtin_amdgcn_global_load_lds(                                         \
          (const __attribute__((address_space(1))) void*)(src + (base16 + lane) * 8), \
          (__attribute__((address_space(3))) void*)(Bt + base16 * 8),           \
          16, 0, 0);                                                            \
    }                                                                           \
  }

#define ASTAGE(TT)                                                              \
  {                                                                             \
    int sel_ = ((TT) >> 2) & 1;                                                 \
    unsigned short* dst_ = At[(TT) & 1];                                        \
    const char* gb_ = (const char*)(xbn + ((TT) & 3) * 64 + cpair);             \
    _Pragma("unroll")                                                           \
    for (int j = 0; j < 4; ++j) {                                               \
      int r_ = w * 8 + j * 2 + half;                                            \
      float4 wv_ = cw[sel_][r_];                                                \
      int4   pv_ = cp[sel_][r_];                                                \
      uint32_t u00 = *(const uint32_t*)(gb_ + pv_.x);                           \
      uint32_t u01 = *(const uint32_t*)(gb_ + pv_.y);                           \
      uint32_t u10 = *(const uint32_t*)(gb_ + pv_.z);                           \
      uint32_t u11 = *(const uint32_t*)(gb_ + pv_.w);                           \
      float a0 = bflo(u00) * wv_.x + bflo(u01) * wv_.y + bflo(u10) * wv_.z + bflo(u11) * wv_.w; \
      float a1 = bfhi(u00) * wv_.x + bfhi(u01) * wv_.y + bfhi(u10) * wv_.z + bfhi(u11) * wv_.w; \
      *(uint32_t*)(&dst_[r_ * 72 + cpair]) = packbf(a0, a1);                    \
    }                                                                           \
  }

  // prologue: stage chunk 0
  BDMA(0)
  ASTAGE(0)
  __syncthreads();

  short8 bfr[2][4];

  for (int t = 0; t < 36; ++t) {
    int cur = t & 1;

    // preload B fragments for chunk t (Bt gets overwritten after barrier)
#pragma unroll
    for (int ks = 0; ks < 2; ++ks)
#pragma unroll
      for (int nn = 0; nn < 4; ++nn) {
        int oc  = wcol * 64 + nn * 16 + mrow;
        int g16 = oc * 8 + ((ks * 4 + quad) ^ (mrow & 7));
        bfr[ks][nn] = *(const short8*)(Bt + g16 * 8);
      }
    __syncthreads();   // all waves' Bt reads done -> safe to DMA-overwrite

    if (t < 35) {
      int s = t + 1;
      BDMA(s)
      ASTAGE(s)
      if ((s & 3) == 0 && s < 32 && tid < 64)
        compute_coords(bn, oh, (s >> 2) + 1, tid, offset,
                       &cw[((s >> 2) + 1) & 1][tid], &cp[((s >> 2) + 1) & 1][tid]);
    }

    // MFMA chunk t: af read lazily from At[cur] (not overwritten this iter)
#pragma unroll
    for (int ks = 0; ks < 2; ++ks) {
      short8 af[2];
#pragma unroll
      for (int m = 0; m < 2; ++m)
        af[m] = *(const short8*)(&At[cur][(wrow * 32 + m * 16 + mrow) * 72 + ks * 32 + quad * 8]);
#pragma unroll
      for (int m = 0; m < 2; ++m)
#pragma unroll
        for (int nn = 0; nn < 4; ++nn)
          acc[m][nn] = __builtin_amdgcn_mfma_f32_16x16x32_bf16(af[m], bfr[ks][nn], acc[m][nn], 0, 0, 0);
    }
    __syncthreads();   // staging of t+1 complete before next iter reads
  }

  // ---- epilogue: C/D layout col=lane&15(oc), row=quad*4+reg(ow) ----
  float* outp = out + (size_t)(bn * 256) * 4096 + oh * 64;
#pragma unroll
  for (int m = 0; m < 2; ++m) {
    int ow0 = wrow * 32 + m * 16 + quad * 4;
#pragma unroll
    for (int nn = 0; nn < 4; ++nn) {
      int oc = wcol * 64 + nn * 16 + mrow;
      *(f32x4*)(outp + oc * 4096 + ow0) = acc[m][nn];
    }
  }
#undef BDMA
#undef ASTAGE
}

extern "C" void kernel_launch(void* const* d_in, const int* in_sizes, int n_in,
                              void* d_out, int out_size, void* d_ws, size_t ws_size,
                              hipStream_t stream) {
  (void)in_sizes; (void)n_in; (void)out_size; (void)ws_size;
  const float* x      = (const float*)d_in[0];
  const float* offset = (const float*)d_in[1];
  const float* weight = (const float*)d_in[2];
  float* out = (float*)d_out;

  unsigned short* xb  = (unsigned short*)d_ws;                                   // 16.78 MB
  unsigned short* w3s = (unsigned short*)((char*)d_ws + (size_t)8*64*64*256*2);  // +1.18 MB

  prep_x_kernel<<<2048, 256, 0, stream>>>(x, xb);
  prep_w_kernel<<<2304, 256, 0, stream>>>(weight, w3s);
  deform_mfma_kernel<<<512, 512, 0, stream>>>(xb, offset, w3s, out);
}

// Round 7
// 155.276 us; speedup vs baseline: 1.9533x; 1.0370x over previous
//
#include <hip/hip_runtime.h>
#include <hip/hip_bf16.h>
#include <hip/hip_fp16.h>
#include <stdint.h>

// deform_conv2d: N=8, C=256, H=W=64, OC=256, 3x3, stride=1, pad=1 -> OH=OW=64
// im2col-fused MFMA GEMM. M=32768 (n,oh,ow), N=256 oc, K=2304 (kd = k*256+c).
// R6: VALU cut -- 16B bilinear gathers (1 thread = 1 row x 8ch unit: 4 dwordx4
//     corner loads + 1 ds_write_b128), coords precomputed+packed (f16 w, u16 pix)
//     by prep, full af+bfr register preload so MFMA(t) has no LDS dependence and
//     overlaps stage(t+1). Single At/Bt buffers, 41 KB LDS. XCD swizzle kept.
// R6b: packbf via __float2bfloat16 pair (bit_cast of __hip_bfloat162 rejected).

typedef short short8 __attribute__((ext_vector_type(8)));
typedef float f32x4 __attribute__((ext_vector_type(4)));

__device__ __forceinline__ float bflo(uint32_t u) { return __uint_as_float(u << 16); }
__device__ __forceinline__ float bfhi(uint32_t u) { return __uint_as_float(u & 0xffff0000u); }
__device__ __forceinline__ uint32_t packbf(float a, float b) {
  unsigned short ua = __builtin_bit_cast(unsigned short, __float2bfloat16(a));
  unsigned short ub = __builtin_bit_cast(unsigned short, __float2bfloat16(b));
  return (uint32_t)ua | ((uint32_t)ub << 16);
}
__device__ __forceinline__ float h2f(uint32_t bits16) {
  __half h = __builtin_bit_cast(__half, (unsigned short)bits16);
  return __half2float(h);
}

// ---- prep 1: x NCHW fp32 -> NHWC bf16 (LDS transpose, vectorized) ----
__global__ __launch_bounds__(256) void prep_x_kernel(const float* __restrict__ x,
                                                     unsigned short* __restrict__ xb) {
  __shared__ float tile[64][65];
  int bn   = blockIdx.x >> 8;
  int rem  = blockIdx.x & 255;
  int y    = rem >> 2;
  int cblk = rem & 3;
  int tid  = threadIdx.x;
  const float* src = x + ((size_t)(bn * 256 + cblk * 64)) * 4096 + y * 64;
#pragma unroll
  for (int i = 0; i < 4; ++i) {
    int u  = i * 256 + tid;
    int cl = u >> 4;
    int xs = (u & 15) * 4;
    float4 v = *(const float4*)(src + cl * 4096 + xs);
    tile[cl][xs] = v.x; tile[cl][xs + 1] = v.y;
    tile[cl][xs + 2] = v.z; tile[cl][xs + 3] = v.w;
  }
  __syncthreads();
  unsigned short* dst = xb + ((size_t)(bn * 64 + y) * 64) * 256 + cblk * 64;
#pragma unroll
  for (int i = 0; i < 8; ++i) {
    int v2  = i * 256 + tid;
    int xc  = v2 >> 5;
    int cl2 = (v2 & 31) * 2;
    *(uint32_t*)(dst + xc * 256 + cl2) = packbf(tile[cl2][xc], tile[cl2 + 1][xc]);
  }
}

// ---- prep 2 (merged): weights -> swizzled bf16 image; offsets -> packed coords ----
// blocks [0,2304): w3s unit g per chunk t: oc=g>>3, kk8=(g&7)^(oc&7).
// blocks [2304,3456): coord entry per (bn,tap,oh,ow): {4 x f16 w, 4 x u16 pix}.
__global__ __launch_bounds__(256) void prep_wc_kernel(const float* __restrict__ w,
                                                      const float* __restrict__ offset,
                                                      unsigned short* __restrict__ w3s,
                                                      unsigned short* __restrict__ coords) {
  if (blockIdx.x < 2304) {
    int idx = blockIdx.x * 256 + threadIdx.x;   // < 589824
    int t   = idx >> 14;
    int r2  = idx & 16383;
    int g   = r2 >> 3;
    int e   = r2 & 7;
    int oc  = g >> 3;
    int kk8 = (g & 7) ^ (oc & 7);
    int kk  = kk8 * 8 + e;
    int c   = (t & 3) * 64 + kk;
    int k   = t >> 2;
    w3s[idx] = __builtin_bit_cast(unsigned short, __float2bfloat16(w[(oc * 256 + c) * 9 + k]));
  } else {
    int idx = (blockIdx.x - 2304) * 256 + threadIdx.x;   // < 294912
    int ow  = idx & 63;
    int oh  = (idx >> 6) & 63;
    int r   = idx >> 12;          // bn*9 + k
    int k   = r % 9;
    int bn  = r / 9;
    int ky = k / 3 - 1;
    int kx = k % 3 - 1;
    float offy = offset[((bn * 18 + 2 * k    ) * 64 + oh) * 64 + ow];
    float offx = offset[((bn * 18 + 2 * k + 1) * 64 + oh) * 64 + ow];
    float y = (float)(oh + ky) + offy;
    float x = (float)(ow + kx) + offx;
    float y0f = floorf(y), x0f = floorf(x);
    float fy = y - y0f, fx = x - x0f;
    int y0 = (int)y0f, x0 = (int)x0f;
    int y1 = y0 + 1, x1 = x0 + 1;
    float vy0 = (y0 >= 0 && y0 <= 63) ? 1.0f : 0.0f;
    float vy1 = (y1 >= 0 && y1 <= 63) ? 1.0f : 0.0f;
    float vx0 = (x0 >= 0 && x0 <= 63) ? 1.0f : 0.0f;
    float vx1 = (x1 >= 0 && x1 <= 63) ? 1.0f : 0.0f;
    float wy0 = (1.0f - fy) * vy0, wy1 = fy * vy1;
    float wx0 = (1.0f - fx) * vx0, wx1 = fx * vx1;
    int y0c = min(max(y0, 0), 63), y1c = min(max(y1, 0), 63);
    int x0c = min(max(x0, 0), 63), x1c = min(max(x1, 0), 63);
    unsigned short ent[8];
    ent[0] = __builtin_bit_cast(unsigned short, __float2half(wy0 * wx0));
    ent[1] = __builtin_bit_cast(unsigned short, __float2half(wy0 * wx1));
    ent[2] = __builtin_bit_cast(unsigned short, __float2half(wy1 * wx0));
    ent[3] = __builtin_bit_cast(unsigned short, __float2half(wy1 * wx1));
    ent[4] = (unsigned short)(y0c * 64 + x0c);
    ent[5] = (unsigned short)(y0c * 64 + x1c);
    ent[6] = (unsigned short)(y1c * 64 + x0c);
    ent[7] = (unsigned short)(y1c * 64 + x1c);
    *(uint4*)(coords + (size_t)idx * 8) = *(const uint4*)ent;
  }
}

// ---- main: 512 blocks x 512 threads; block tile 64 rows x 256 oc; wave 32x64 ----
__global__ __launch_bounds__(512, 4) void deform_mfma_kernel(
    const unsigned short* __restrict__ xb,      // NHWC bf16
    const unsigned short* __restrict__ coords,  // packed coord entries
    const unsigned short* __restrict__ w3s,     // swizzled chunk-major bf16
    float* __restrict__ out) {                  // (8, 256, 64, 64) fp32
  __shared__ __align__(16) unsigned short At[64 * 72];   // 9216 B (single)
  __shared__ __align__(16) unsigned short Bt[256 * 64];  // 32768 B (single, swizzled)

  int bn  = blockIdx.x & 7;      // XCD swizzle
  int oh  = blockIdx.x >> 3;
  int tid = threadIdx.x;

  int w     = tid >> 6;            // wave 0..7
  int lane  = tid & 63;
  int wrow  = w & 1;               // row half (32 rows)
  int wcol  = w >> 1;              // oc quarter (64 oc)
  int mrow  = lane & 15;
  int quad  = lane >> 4;

  // staging identity: one thread = one (row, 8-ch group) unit
  int srow = tid >> 3;             // 0..63
  int sg   = tid & 7;              // channel group

  const unsigned short* xbn = xb + (size_t)bn * (64 * 64 * 256);
  // per-thread bases (chunk-invariant)
  const char* gbase = (const char*)xbn + sg * 16;            // + (t&3)*128 + pix*512
  const unsigned short* cbase = coords + ((size_t)((bn * 9) * 64 + oh) * 64 + srow) * 8;

  f32x4 acc[2][4] = {};

#define BDMA(TT)                                                                \
  {                                                                             \
    const unsigned short* src = w3s + (TT) * 16384;                             \
    _Pragma("unroll")                                                           \
    for (int j = 0; j < 4; ++j) {                                               \
      int base16 = j * 512 + w * 64;                                            \
      __builtin_amdgcn_global_load_lds(                                         \
          (const __attribute__((address_space(1))) void*)(src + (base16 + lane) * 8), \
          (__attribute__((address_space(3))) void*)(Bt + base16 * 8),           \
          16, 0, 0);                                                            \
    }                                                                           \
  }

  // one 16B bilinear-sample unit per thread
#define ASTAGE(TT)                                                              \
  {                                                                             \
    uint4 e = *(const uint4*)(cbase + ((TT) >> 2) * 32768);                     \
    const char* gb = gbase + ((TT) & 3) * 128;                                  \
    uint4 c00 = *(const uint4*)(gb + ((e.z & 0xffffu) << 9));                   \
    uint4 c01 = *(const uint4*)(gb + ((e.z >> 16) << 9));                       \
    uint4 c10 = *(const uint4*)(gb + ((e.w & 0xffffu) << 9));                   \
    uint4 c11 = *(const uint4*)(gb + ((e.w >> 16) << 9));                       \
    float w00 = h2f(e.x & 0xffffu), w01 = h2f(e.x >> 16);                       \
    float w10 = h2f(e.y & 0xffffu), w11 = h2f(e.y >> 16);                       \
    float a0 = bflo(c00.x) * w00 + bflo(c01.x) * w01 + bflo(c10.x) * w10 + bflo(c11.x) * w11; \
    float a1 = bfhi(c00.x) * w00 + bfhi(c01.x) * w01 + bfhi(c10.x) * w10 + bfhi(c11.x) * w11; \
    float a2 = bflo(c00.y) * w00 + bflo(c01.y) * w01 + bflo(c10.y) * w10 + bflo(c11.y) * w11; \
    float a3 = bfhi(c00.y) * w00 + bfhi(c01.y) * w01 + bfhi(c10.y) * w10 + bfhi(c11.y) * w11; \
    float a4 = bflo(c00.z) * w00 + bflo(c01.z) * w01 + bflo(c10.z) * w10 + bflo(c11.z) * w11; \
    float a5 = bfhi(c00.z) * w00 + bfhi(c01.z) * w01 + bfhi(c10.z) * w10 + bfhi(c11.z) * w11; \
    float a6 = bflo(c00.w) * w00 + bflo(c01.w) * w01 + bflo(c10.w) * w10 + bflo(c11.w) * w11; \
    float a7 = bfhi(c00.w) * w00 + bfhi(c01.w) * w01 + bfhi(c10.w) * w10 + bfhi(c11.w) * w11; \
    uint4 pk;                                                                   \
    pk.x = packbf(a0, a1); pk.y = packbf(a2, a3);                               \
    pk.z = packbf(a4, a5); pk.w = packbf(a6, a7);                               \
    *(uint4*)(&At[srow * 72 + sg * 8]) = pk;                                    \
  }

  // prologue: stage chunk 0
  BDMA(0)
  ASTAGE(0)
  __syncthreads();

  short8 af[2][2];
  short8 bfr[2][4];

  for (int t = 0; t < 36; ++t) {
    // ---- preload all fragments for chunk t into registers ----
#pragma unroll
    for (int ks = 0; ks < 2; ++ks) {
#pragma unroll
      for (int m = 0; m < 2; ++m)
        af[m][ks] = *(const short8*)(&At[(wrow * 32 + m * 16 + mrow) * 72 + ks * 32 + quad * 8]);
#pragma unroll
      for (int nn = 0; nn < 4; ++nn) {
        int oc  = wcol * 64 + nn * 16 + mrow;
        int g16 = oc * 8 + ((ks * 4 + quad) ^ (mrow & 7));
        bfr[ks][nn] = *(const short8*)(Bt + g16 * 8);
      }
    }
    __syncthreads();   // all waves done reading At/Bt -> safe to overwrite

    // ---- stage chunk t+1 (global->LDS) while MFMA(t) runs from registers ----
    if (t < 35) {
      BDMA(t + 1)
      ASTAGE(t + 1)
    }
#pragma unroll
    for (int ks = 0; ks < 2; ++ks)
#pragma unroll
      for (int m = 0; m < 2; ++m)
#pragma unroll
        for (int nn = 0; nn < 4; ++nn)
          acc[m][nn] = __builtin_amdgcn_mfma_f32_16x16x32_bf16(af[m][ks], bfr[ks][nn], acc[m][nn], 0, 0, 0);
    __syncthreads();   // staging complete before next preload
  }

  // ---- epilogue: C/D layout col=lane&15(oc), row=quad*4+reg(ow) ----
  float* outp = out + (size_t)(bn * 256) * 4096 + oh * 64;
#pragma unroll
  for (int m = 0; m < 2; ++m) {
    int ow0 = wrow * 32 + m * 16 + quad * 4;
#pragma unroll
    for (int nn = 0; nn < 4; ++nn) {
      int oc = wcol * 64 + nn * 16 + mrow;
      *(f32x4*)(outp + oc * 4096 + ow0) = acc[m][nn];
    }
  }
#undef BDMA
#undef ASTAGE
}

extern "C" void kernel_launch(void* const* d_in, const int* in_sizes, int n_in,
                              void* d_out, int out_size, void* d_ws, size_t ws_size,
                              hipStream_t stream) {
  (void)in_sizes; (void)n_in; (void)out_size; (void)ws_size;
  const float* x      = (const float*)d_in[0];
  const float* offset = (const float*)d_in[1];
  const float* weight = (const float*)d_in[2];
  float* out = (float*)d_out;

  unsigned short* xb     = (unsigned short*)d_ws;                        // 16.78 MB
  unsigned short* w3s    = xb + (size_t)8 * 64 * 64 * 256;               // +1.18 MB
  unsigned short* coords = w3s + (size_t)36 * 16384;                     // +4.72 MB

  prep_x_kernel<<<2048, 256, 0, stream>>>(x, xb);
  prep_wc_kernel<<<3456, 256, 0, stream>>>(weight, offset, w3s, coords);
  deform_mfma_kernel<<<512, 512, 0, stream>>>(xb, coords, w3s, out);
}